// Round 13
// baseline (486.594 us; speedup 1.0000x reference)
//
#include <hip/hip_runtime.h>
#include <cmath>

#define DM 512
#define DS 256
#define NL 4
#define BATCH 8
#define SEQ 2048
#define MROWS (BATCH*SEQ)   // 16384
#define LCH 32
#define NCH 64              // LCH*NCH == SEQ

typedef unsigned short ushort_t;
typedef unsigned int uint_t;
typedef __attribute__((ext_vector_type(8))) short short8;
typedef __attribute__((ext_vector_type(4))) float floatx4;

__device__ __forceinline__ float sigmoidf_(float v) { return 1.0f / (1.0f + __expf(-v)); }

__device__ __forceinline__ ushort_t f2bf(float f) {
    union { float f; unsigned int u; } c; c.f = f;
    unsigned int u = c.u;
    u += 0x7fffu + ((u >> 16) & 1u);          // RNE
    return (ushort_t)(u >> 16);
}
__device__ __forceinline__ float bf2f(uint_t h) {
    union { unsigned int u; float f; } c; c.u = (h & 0xffffu) << 16; return c.f;
}
__device__ __forceinline__ uint_t pack2(float a, float b) {
    return (uint_t)f2bf(a) | ((uint_t)f2bf(b) << 16);
}

#define AS1 __attribute__((address_space(1)))
#define AS3 __attribute__((address_space(3)))
__device__ __forceinline__ void gl_lds16(const void* g, void* l) {
    __builtin_amdgcn_global_load_lds((const AS1 uint_t*)g, (AS3 uint_t*)l, 16, 0, 0);
}

// All GEMM arguments in one struct: no positional-arity pitfalls.
struct GemmArgs {
    const ushort_t* A;       // [M,K] bf16
    const ushort_t* Wa;      // [N,K] bf16
    const ushort_t* Wb;      // [N,K] bf16 (DUAL only)
    const ushort_t* xbf_in;  // EPI2/EPI3: bf16 x
    const float* gam;        // EPI1
    const float* Dv;         // EPI2
    float* of32;             // EPI4
    ushort_t* obf;           // EPI0..3
    const float* resp;       // EPI3
    int K;
    int N;
    int layer;
};

// ---------------------------------------------------------------------------
// bf16 MFMA GEMM, double-buffered async global->LDS staging, LDS-transpose
// epilogue. O = A[M,K] @ W[N,K]^T. EPI:
//  0: encoder  -> obf = bf16(acc)
//  1: Bu       -> obf = bf16(acc * gam[col>>1])        (interleaved re/im cols)
//  2: z        -> obf = bf16(acc + Dv[col]*bf2f(xbf_in[row,col]))
//  3: GLU dual -> obf = bf16(bf2f(xbf_in) + sigmoid(resp[l])*acc0*sigmoid(acc1))
//  4: plain    -> of32 = acc   (decoder, BN=64, direct store)
// R13: occupancy bump — single-W dbuf 32KB -> 4 blocks/CU, dual 48KB -> 3.
// ---------------------------------------------------------------------------
#define PREFETCH_TILE(it_, buf_)                                                        \
    do {                                                                                \
        const size_t kb_ = (size_t)(it_) * 64;                                          \
        char* dst_ = smem + (buf_) * HALF;                                              \
        gl_lds16(Ap + (size_t)(wid * 16 + lrow) * Kb + kb_, dst_ + wid * 1024);         \
        gl_lds16(Ap + (size_t)((wid + 4) * 16 + lrow) * Kb + kb_,                       \
                 dst_ + (wid + 4) * 1024);                                              \
        gl_lds16(B0p + (size_t)(wid * 16 + lrow) * Kb + kb_, dst_ + AB + wid * 1024);   \
        if constexpr (BN == 128) {                                                      \
            gl_lds16(B0p + (size_t)((wid + 4) * 16 + lrow) * Kb + kb_,                  \
                     dst_ + AB + (wid + 4) * 1024);                                     \
        }                                                                               \
        if constexpr (DUAL) {                                                           \
            gl_lds16(B1p + (size_t)(wid * 16 + lrow) * Kb + kb_,                        \
                     dst_ + AB + BB + wid * 1024);                                      \
            if constexpr (BN == 128) {                                                  \
                gl_lds16(B1p + (size_t)((wid + 4) * 16 + lrow) * Kb + kb_,              \
                         dst_ + AB + BB + (wid + 4) * 1024);                            \
            }                                                                           \
        }                                                                               \
    } while (0)

template<int BN, int EPI, int DUAL>
__launch_bounds__(256, DUAL ? 3 : 4)
__global__ void mgemm(const GemmArgs p) {
    constexpr int BM = 128;
    constexpr int MT = (BN == 128) ? 4 : 2;
    constexpr int NT = 4;
    constexpr int WROWS = MT * 16;
    constexpr int AB = 8192;                         // A stage bytes (128 x 64B)
    constexpr int BB = (BN == 128) ? 8192 : 4096;
    constexpr int B1B = DUAL ? BB : 0;
    constexpr int HALF = AB + BB + B1B;              // one pipeline stage
    constexpr int EPB = (EPI == 4) ? 0 : 32 * 132 * 4;
    constexpr int SMB = (2 * HALF > EPB) ? 2 * HALF : EPB;
    __shared__ __align__(16) char smem[SMB];

    const int K = p.K, N = p.N;
    const int tid = threadIdx.x, lane = tid & 63, wid = tid >> 6;
    const int wm = (BN == 128) ? (wid & 1) : wid;
    const int wn = (BN == 128) ? (wid >> 1) : 0;
    const int m0 = blockIdx.x * BM, n0 = blockIdx.y * BN;
    const int q = lane >> 4, r16 = lane & 15;
    const int lrow = lane >> 2;
    const size_t Kb = (size_t)K * 2;                 // row bytes
    const char* Ap  = (const char*)p.A  + (size_t)m0 * Kb + (lane & 3) * 16;
    const char* B0p = (const char*)p.Wa + (size_t)n0 * Kb + (lane & 3) * 16;
    const char* B1p = (const char*)p.Wb + (size_t)n0 * Kb + (lane & 3) * 16;

    floatx4 acc0[MT][NT] = {};
    floatx4 acc1[DUAL ? MT : 1][DUAL ? NT : 1] = {};

    const int iters = K >> 5;
    PREFETCH_TILE(0, 0);
    for (int it = 0; it < iters; ++it) {
        __syncthreads();
        if (it + 1 < iters) PREFETCH_TILE(it + 1, (it + 1) & 1);
        const ushort_t* As  = (const ushort_t*)(smem + (it & 1) * HALF);
        const ushort_t* Bs0 = (const ushort_t*)(smem + (it & 1) * HALF + AB);
        const ushort_t* Bs1 = (const ushort_t*)(smem + (it & 1) * HALF + AB + BB);

        short8 af[MT], b0[NT], b1[DUAL ? NT : 1];
#pragma unroll
        for (int i = 0; i < MT; ++i)
            af[i] = *(const short8*)&As[(wm * WROWS + i * 16 + r16) * 32 + q * 8];
#pragma unroll
        for (int j = 0; j < NT; ++j) {
            b0[j] = *(const short8*)&Bs0[(wn * 64 + j * 16 + r16) * 32 + q * 8];
            if constexpr (DUAL)
                b1[j] = *(const short8*)&Bs1[(wn * 64 + j * 16 + r16) * 32 + q * 8];
        }
#pragma unroll
        for (int i = 0; i < MT; ++i)
#pragma unroll
            for (int j = 0; j < NT; ++j) {
                acc0[i][j] = __builtin_amdgcn_mfma_f32_16x16x32_bf16(af[i], b0[j], acc0[i][j], 0, 0, 0);
                if constexpr (DUAL)
                    acc1[i][j] = __builtin_amdgcn_mfma_f32_16x16x32_bf16(af[i], b1[j], acc1[i][j], 0, 0, 0);
            }
    }

    if constexpr (EPI == 4) {
#pragma unroll
        for (int i = 0; i < MT; ++i)
#pragma unroll
            for (int j = 0; j < NT; ++j)
#pragma unroll
                for (int rr = 0; rr < 4; ++rr) {
                    const int row = m0 + wm * WROWS + i * 16 + q * 4 + rr;
                    const int col = wn * 64 + j * 16 + r16;
                    p.of32[(size_t)row * N + col] = acc0[i][j][rr];
                }
        return;
    } else {
        float* eps = (float*)smem;                    // [32][132]
        float rsv = 0.f;
        if constexpr (EPI == 3) rsv = sigmoidf_(p.resp[p.layer]);

#pragma unroll
        for (int i = 0; i < MT; ++i) {
            __syncthreads();
#pragma unroll
            for (int j = 0; j < NT; ++j) {
                const int colt = wn * 64 + j * 16 + r16;
#pragma unroll
                for (int rr = 0; rr < 4; ++rr) {
                    float v = acc0[i][j][rr];
                    if constexpr (EPI == 1) v *= p.gam[(n0 + colt) >> 1];
                    if constexpr (EPI == 3) v = rsv * v * sigmoidf_(acc1[i][j][rr]);
                    eps[(wm * 16 + q * 4 + rr) * 132 + colt] = v;
                }
            }
            __syncthreads();
            const int row_r = tid >> 3, colg = (tid & 7) * 16;
            const int grow = m0 + (row_r >> 4) * 64 + i * 16 + (row_r & 15);
            const int gcol = n0 + colg;
            float4 f[4];
#pragma unroll
            for (int c = 0; c < 4; ++c) f[c] = *(float4*)&eps[row_r * 132 + colg + c * 4];
            const size_t ob = (size_t)grow * N + gcol;

            if constexpr (EPI == 2) {
                uint_t xp[8];
                *(uint4*)(xp)     = *(const uint4*)(p.xbf_in + ob);
                *(uint4*)(xp + 4) = *(const uint4*)(p.xbf_in + ob + 8);
#pragma unroll
                for (int c = 0; c < 4; ++c) {
                    float4 dv = *(const float4*)(p.Dv + gcol + c * 4);
                    f[c].x += dv.x * bf2f(xp[2 * c]);
                    f[c].y += dv.y * bf2f(xp[2 * c] >> 16);
                    f[c].z += dv.z * bf2f(xp[2 * c + 1]);
                    f[c].w += dv.w * bf2f(xp[2 * c + 1] >> 16);
                }
            } else if constexpr (EPI == 3) {
                uint_t xp[8];
                *(uint4*)(xp)     = *(const uint4*)(p.xbf_in + ob);
                *(uint4*)(xp + 4) = *(const uint4*)(p.xbf_in + ob + 8);
#pragma unroll
                for (int c = 0; c < 4; ++c) {
                    f[c].x += bf2f(xp[2 * c]);
                    f[c].y += bf2f(xp[2 * c] >> 16);
                    f[c].z += bf2f(xp[2 * c + 1]);
                    f[c].w += bf2f(xp[2 * c + 1] >> 16);
                }
            }
            uint4 p0, p1;
            p0.x = pack2(f[0].x, f[0].y); p0.y = pack2(f[0].z, f[0].w);
            p0.z = pack2(f[1].x, f[1].y); p0.w = pack2(f[1].z, f[1].w);
            p1.x = pack2(f[2].x, f[2].y); p1.y = pack2(f[2].z, f[2].w);
            p1.z = pack2(f[3].x, f[3].y); p1.w = pack2(f[3].z, f[3].w);
            *(uint4*)(p.obf + ob) = p0;
            *(uint4*)(p.obf + ob + 8) = p1;
        }
    }
}

// ---------------------------------------------------------------------------
// Single prep kernel: all weight bf16 packing + u cast + lambda/gamma tables.
// ---------------------------------------------------------------------------
__global__ void prep_all(const float* __restrict__ u, const float* __restrict__ enc,
                         const float* __restrict__ dec, const float* __restrict__ nu,
                         const float* __restrict__ th,
                         const float* __restrict__ Bre, const float* __restrict__ Bim,
                         const float* __restrict__ Cre, const float* __restrict__ Cim,
                         const float* __restrict__ W1, const float* __restrict__ W2,
                         ushort_t* __restrict__ WBb, ushort_t* __restrict__ Wzb,
                         ushort_t* __restrict__ W1b, ushort_t* __restrict__ W2b,
                         ushort_t* __restrict__ encb, ushort_t* __restrict__ decb,
                         ushort_t* __restrict__ ubf,
                         float* __restrict__ lre, float* __restrict__ lim,
                         float* __restrict__ gm) {
    const int idx = blockIdx.x * 256 + threadIdx.x;   // 0..1M-1
    const int k = idx & 511, n = (idx >> 9) & 511, l = idx >> 18;
    {
        const int s = n >> 1, part = n & 1;
        const float* src = part ? Bim : Bre;
        WBb[idx] = f2bf(src[((size_t)l * DS + s) * DM + k]);
    }
    {
        const int s = k >> 1, part = k & 1;
        float v = part ? -Cim[((size_t)l * DM + n) * DS + s]
                       :  Cre[((size_t)l * DM + n) * DS + s];
        Wzb[idx] = f2bf(v);
    }
    W1b[idx] = f2bf(W1[idx]);
    W2b[idx] = f2bf(W2[idx]);
    ubf[idx] = f2bf(u[idx]);
    if (idx < DM * 64) { encb[idx] = f2bf(enc[idx]); decb[idx] = f2bf(dec[idx]); }
    if (idx < NL * DS) {
        float a = expf(-expf(nu[idx])), t = expf(th[idx]);
        lre[idx] = a * cosf(t);
        lim[idx] = a * sinf(t);
        gm[idx] = sqrtf(fmaxf(0.f, 1.f - a * a));
    }
}

// ---------------------------------------------------------------------------
// Chunked 3-pass scan on interleaved bf16 (re,im) uints. 512 blocks/pass.
// ---------------------------------------------------------------------------
__global__ void scan_ends(const uint_t* __restrict__ Bu, const float* __restrict__ lre_,
                          const float* __restrict__ lim_, float* __restrict__ carry) {
    const int s = threadIdx.x;
    const int blk = blockIdx.x, b = blk >> 6, c = blk & 63;
    const float lre = lre_[s], lim = lim_[s];
    float hre = 0.f, him = 0.f;
    size_t base = ((size_t)b * SEQ + (size_t)c * LCH) * DS + s;
#pragma unroll 8
    for (int i = 0; i < LCH; ++i, base += DS) {
        uint_t u = Bu[base];
        float br = bf2f(u), bi = bf2f(u >> 16);
        float nr = fmaf(lre, hre, fmaf(-lim, him, br));
        float ni = fmaf(lre, him, fmaf(lim, hre, bi));
        hre = nr; him = ni;
    }
    carry[(size_t)blk * 512 + s] = hre;
    carry[(size_t)blk * 512 + DS + s] = him;
}

__global__ void scan_carry(float* __restrict__ carry, const float* __restrict__ lre_,
                           const float* __restrict__ lim_) {
    const int s = threadIdx.x, b = blockIdx.x;
    float pre = lre_[s], pim = lim_[s];
    for (int t = 0; t < 5; ++t) {            // lam^32 (LCH = 32 = 2^5)
        float nr = pre * pre - pim * pim, ni = 2.f * pre * pim;
        pre = nr; pim = ni;
    }
    size_t base = (size_t)b * NCH * 512 + s;
    float gre = carry[base], gim = carry[base + DS];
    for (int c = 1; c < NCH; ++c) {
        size_t id = base + (size_t)c * 512;
        float cr = carry[id], ci = carry[id + DS];
        float nr = fmaf(pre, gre, fmaf(-pim, gim, cr));
        float ni = fmaf(pre, gim, fmaf(pim, gre, ci));
        gre = nr; gim = ni;
        carry[id] = gre; carry[id + DS] = gim;
    }
}

__global__ void scan_apply(const uint_t* __restrict__ Bu, const float* __restrict__ lre_,
                           const float* __restrict__ lim_, const float* __restrict__ carry,
                           uint_t* __restrict__ h) {
    const int s = threadIdx.x;
    const int blk = blockIdx.x, b = blk >> 6, c = blk & 63;
    const float lre = lre_[s], lim = lim_[s];
    float hre = 0.f, him = 0.f;
    if (c > 0) {
        size_t cb = (size_t)(blk - 1) * 512 + s;
        hre = carry[cb]; him = carry[cb + DS];
    }
    size_t base = ((size_t)b * SEQ + (size_t)c * LCH) * DS + s;
#pragma unroll 8
    for (int i = 0; i < LCH; ++i, base += DS) {
        uint_t u = Bu[base];
        float br = bf2f(u), bi = bf2f(u >> 16);
        float nr = fmaf(lre, hre, fmaf(-lim, him, br));
        float ni = fmaf(lre, him, fmaf(lim, hre, bi));
        hre = nr; him = ni;
        h[base] = pack2(hre, him);
    }
}

// ---------------------------------------------------------------------------
extern "C" void kernel_launch(void* const* d_in, const int* in_sizes, int n_in,
                              void* d_out, int out_size, void* d_ws, size_t ws_size,
                              hipStream_t stream) {
    const float* u   = (const float*)d_in[0];
    const float* enc = (const float*)d_in[1];
    const float* dec = (const float*)d_in[2];
    const float* nu  = (const float*)d_in[3];
    const float* th  = (const float*)d_in[4];
    const float* Bre = (const float*)d_in[5];
    const float* Bim = (const float*)d_in[6];
    const float* Cre = (const float*)d_in[7];
    const float* Cim = (const float*)d_in[8];
    const float* Dp  = (const float*)d_in[9];
    const float* W1  = (const float*)d_in[10];
    const float* W2  = (const float*)d_in[11];
    const float* res = (const float*)d_in[12];
    float* out = (float*)d_out;

    const size_t MD = (size_t)MROWS * DM;
    float* carry = (float*)d_ws;                         // [8*64,512] fp32
    float* lre  = carry + (size_t)BATCH * NCH * 512;
    float* lim  = lre + NL * DS;
    float* gmt  = lim + NL * DS;
    ushort_t* xbf  = (ushort_t*)(gmt + NL * DS);         // bf16 [16384,512] each:
    ushort_t* Bubf = xbf + MD;
    ushort_t* hbf  = Bubf + MD;
    ushort_t* zbf  = hbf + MD;
    ushort_t* ubf  = zbf;                                // alias: z written after u consumed
    ushort_t* WBb  = zbf + MD;                           // weights, 4x512x512 bf16 each:
    ushort_t* Wzb  = WBb + (size_t)NL * DM * DM;
    ushort_t* W1b  = Wzb + (size_t)NL * DM * DM;
    ushort_t* W2b  = W1b + (size_t)NL * DM * DM;
    ushort_t* encb = W2b + (size_t)NL * DM * DM;         // 512x64
    ushort_t* decb = encb + DM * 64;                     // 64x512

    prep_all<<<NL * DM * DM / 256, 256, 0, stream>>>(
        u, enc, dec, nu, th, Bre, Bim, Cre, Cim, W1, W2,
        WBb, Wzb, W1b, W2b, encb, decb, ubf, lre, lim, gmt);

    const dim3 gFull(MROWS / 128, DM / 128);

    // encoder: xbf = bf16(u @ enc^T)
    {
        GemmArgs a = {};
        a.A = ubf; a.Wa = encb; a.K = 64; a.N = DM;
        a.obf = xbf;
        mgemm<128, 0, 0><<<gFull, 256, 0, stream>>>(a);
    }

    for (int k = 0; k < NL; ++k) {
        {   // Bu (interleaved re/im cols, gamma-scaled) -> Bubf
            GemmArgs a = {};
            a.A = xbf; a.Wa = WBb + (size_t)k * DM * DM; a.K = DM; a.N = DM;
            a.obf = Bubf; a.gam = gmt + k * DS;
            mgemm<128, 1, 0><<<gFull, 256, 0, stream>>>(a);
        }
        scan_ends<<<BATCH * NCH, 256, 0, stream>>>((const uint_t*)Bubf,
                                                   lre + k * DS, lim + k * DS, carry);
        scan_carry<<<BATCH, 256, 0, stream>>>(carry, lre + k * DS, lim + k * DS);
        scan_apply<<<BATCH * NCH, 256, 0, stream>>>((const uint_t*)Bubf,
                                                    lre + k * DS, lim + k * DS, carry,
                                                    (uint_t*)hbf);
        {   // z = Re(h @ C^T) + D*x  -> zbf
            GemmArgs a = {};
            a.A = hbf; a.Wa = Wzb + (size_t)k * DM * DM; a.K = DM; a.N = DM;
            a.obf = zbf; a.xbf_in = xbf; a.Dv = Dp + k * DM;
            mgemm<128, 2, 0><<<gFull, 256, 0, stream>>>(a);
        }
        {   // xbf += sig(res)*[(z@W1^T)*sigmoid(z@W2^T)]   (bf16 RMW)
            GemmArgs a = {};
            a.A = zbf; a.Wa = W1b + (size_t)k * DM * DM; a.Wb = W2b + (size_t)k * DM * DM;
            a.K = DM; a.N = DM;
            a.obf = xbf; a.xbf_in = xbf; a.resp = res; a.layer = k;
            mgemm<128, 3, 1><<<gFull, 256, 0, stream>>>(a);
        }
    }
    {   // decoder: out = x @ dec^T
        GemmArgs a = {};
        a.A = xbf; a.Wa = decb; a.K = DM; a.N = 64;
        a.of32 = out;
        mgemm<64, 4, 0><<<dim3(MROWS / 128, 1), 256, 0, stream>>>(a);
    }
}

// Round 14
// 378.278 us; speedup vs baseline: 1.2863x; 1.2863x over previous
//
#include <hip/hip_runtime.h>
#include <cmath>

#define DM 512
#define DS 256
#define NL 4
#define BATCH 8
#define SEQ 2048
#define MROWS (BATCH*SEQ)   // 16384
#define LCH 32
#define NCH 64              // LCH*NCH == SEQ

typedef unsigned short ushort_t;
typedef unsigned int uint_t;
typedef __attribute__((ext_vector_type(8))) short short8;
typedef __attribute__((ext_vector_type(4))) float floatx4;

__device__ __forceinline__ float sigmoidf_(float v) { return 1.0f / (1.0f + __expf(-v)); }

__device__ __forceinline__ ushort_t f2bf(float f) {
    union { float f; unsigned int u; } c; c.f = f;
    unsigned int u = c.u;
    u += 0x7fffu + ((u >> 16) & 1u);          // RNE
    return (ushort_t)(u >> 16);
}
__device__ __forceinline__ float bf2f(uint_t h) {
    union { unsigned int u; float f; } c; c.u = (h & 0xffffu) << 16; return c.f;
}
__device__ __forceinline__ uint_t pack2(float a, float b) {
    return (uint_t)f2bf(a) | ((uint_t)f2bf(b) << 16);
}

#define AS1 __attribute__((address_space(1)))
#define AS3 __attribute__((address_space(3)))
__device__ __forceinline__ void gl_lds16(const void* g, void* l) {
    __builtin_amdgcn_global_load_lds((const AS1 uint_t*)g, (AS3 uint_t*)l, 16, 0, 0);
}

// All GEMM arguments in one struct: no positional-arity pitfalls.
struct GemmArgs {
    const ushort_t* A;       // [M,K] bf16
    const ushort_t* Wa;      // [N,K] bf16
    const ushort_t* Wb;      // [N,K] bf16 (DUAL only)
    const ushort_t* xbf_in;  // EPI2/EPI3: bf16 x
    const float* gam;        // EPI1
    const float* Dv;         // EPI2
    float* of32;             // EPI4
    ushort_t* obf;           // EPI0..3
    const float* resp;       // EPI3
    int K;
    int N;
    int layer;
};

// ---------------------------------------------------------------------------
// bf16 MFMA GEMM, double-buffered async global->LDS staging, LDS-transpose
// epilogue. O = A[M,K] @ W[N,K]^T. EPI:
//  0: encoder  -> obf = bf16(acc)
//  1: Bu       -> obf = bf16(acc * gam[col>>1])        (interleaved re/im cols)
//  2: z        -> obf = bf16(acc + Dv[col]*bf2f(xbf_in[row,col]))
//  3: GLU dual -> obf = bf16(bf2f(xbf_in) + sigmoid(resp[l])*acc0*sigmoid(acc1))
//  4: plain    -> of32 = acc   (decoder, BN=64, direct store)
// launch_bounds 3 (single) / 2 (dual): dual needs >=128 VGPR for acc alone —
// bound 3 forces spills (R13: VGPR 84, +27MB scratch traffic, 28->55us).
// ---------------------------------------------------------------------------
#define PREFETCH_TILE(it_, buf_)                                                        \
    do {                                                                                \
        const size_t kb_ = (size_t)(it_) * 64;                                          \
        char* dst_ = smem + (buf_) * HALF;                                              \
        gl_lds16(Ap + (size_t)(wid * 16 + lrow) * Kb + kb_, dst_ + wid * 1024);         \
        gl_lds16(Ap + (size_t)((wid + 4) * 16 + lrow) * Kb + kb_,                       \
                 dst_ + (wid + 4) * 1024);                                              \
        gl_lds16(B0p + (size_t)(wid * 16 + lrow) * Kb + kb_, dst_ + AB + wid * 1024);   \
        if constexpr (BN == 128) {                                                      \
            gl_lds16(B0p + (size_t)((wid + 4) * 16 + lrow) * Kb + kb_,                  \
                     dst_ + AB + (wid + 4) * 1024);                                     \
        }                                                                               \
        if constexpr (DUAL) {                                                           \
            gl_lds16(B1p + (size_t)(wid * 16 + lrow) * Kb + kb_,                        \
                     dst_ + AB + BB + wid * 1024);                                      \
            if constexpr (BN == 128) {                                                  \
                gl_lds16(B1p + (size_t)((wid + 4) * 16 + lrow) * Kb + kb_,              \
                         dst_ + AB + BB + (wid + 4) * 1024);                            \
            }                                                                           \
        }                                                                               \
    } while (0)

template<int BN, int EPI, int DUAL>
__launch_bounds__(256, DUAL ? 2 : 3)
__global__ void mgemm(const GemmArgs p) {
    constexpr int BM = 128;
    constexpr int MT = (BN == 128) ? 4 : 2;
    constexpr int NT = 4;
    constexpr int WROWS = MT * 16;
    constexpr int AB = 8192;                         // A stage bytes (128 x 64B)
    constexpr int BB = (BN == 128) ? 8192 : 4096;
    constexpr int B1B = DUAL ? BB : 0;
    constexpr int HALF = AB + BB + B1B;              // one pipeline stage
    constexpr int EPB = (EPI == 4) ? 0 : 32 * 132 * 4;
    constexpr int SMB = (2 * HALF > EPB) ? 2 * HALF : EPB;
    __shared__ __align__(16) char smem[SMB];

    const int K = p.K, N = p.N;
    const int tid = threadIdx.x, lane = tid & 63, wid = tid >> 6;
    const int wm = (BN == 128) ? (wid & 1) : wid;
    const int wn = (BN == 128) ? (wid >> 1) : 0;
    const int m0 = blockIdx.x * BM, n0 = blockIdx.y * BN;
    const int q = lane >> 4, r16 = lane & 15;
    const int lrow = lane >> 2;
    const size_t Kb = (size_t)K * 2;                 // row bytes
    const char* Ap  = (const char*)p.A  + (size_t)m0 * Kb + (lane & 3) * 16;
    const char* B0p = (const char*)p.Wa + (size_t)n0 * Kb + (lane & 3) * 16;
    const char* B1p = (const char*)p.Wb + (size_t)n0 * Kb + (lane & 3) * 16;

    floatx4 acc0[MT][NT] = {};
    floatx4 acc1[DUAL ? MT : 1][DUAL ? NT : 1] = {};

    const int iters = K >> 5;
    PREFETCH_TILE(0, 0);
    for (int it = 0; it < iters; ++it) {
        __syncthreads();
        if (it + 1 < iters) PREFETCH_TILE(it + 1, (it + 1) & 1);
        const ushort_t* As  = (const ushort_t*)(smem + (it & 1) * HALF);
        const ushort_t* Bs0 = (const ushort_t*)(smem + (it & 1) * HALF + AB);
        const ushort_t* Bs1 = (const ushort_t*)(smem + (it & 1) * HALF + AB + BB);

        short8 af[MT], b0[NT], b1[DUAL ? NT : 1];
#pragma unroll
        for (int i = 0; i < MT; ++i)
            af[i] = *(const short8*)&As[(wm * WROWS + i * 16 + r16) * 32 + q * 8];
#pragma unroll
        for (int j = 0; j < NT; ++j) {
            b0[j] = *(const short8*)&Bs0[(wn * 64 + j * 16 + r16) * 32 + q * 8];
            if constexpr (DUAL)
                b1[j] = *(const short8*)&Bs1[(wn * 64 + j * 16 + r16) * 32 + q * 8];
        }
#pragma unroll
        for (int i = 0; i < MT; ++i)
#pragma unroll
            for (int j = 0; j < NT; ++j) {
                acc0[i][j] = __builtin_amdgcn_mfma_f32_16x16x32_bf16(af[i], b0[j], acc0[i][j], 0, 0, 0);
                if constexpr (DUAL)
                    acc1[i][j] = __builtin_amdgcn_mfma_f32_16x16x32_bf16(af[i], b1[j], acc1[i][j], 0, 0, 0);
            }
    }

    if constexpr (EPI == 4) {
#pragma unroll
        for (int i = 0; i < MT; ++i)
#pragma unroll
            for (int j = 0; j < NT; ++j)
#pragma unroll
                for (int rr = 0; rr < 4; ++rr) {
                    const int row = m0 + wm * WROWS + i * 16 + q * 4 + rr;
                    const int col = wn * 64 + j * 16 + r16;
                    p.of32[(size_t)row * N + col] = acc0[i][j][rr];
                }
        return;
    } else {
        float* eps = (float*)smem;                    // [32][132]
        float rsv = 0.f;
        if constexpr (EPI == 3) rsv = sigmoidf_(p.resp[p.layer]);

#pragma unroll
        for (int i = 0; i < MT; ++i) {
            __syncthreads();
#pragma unroll
            for (int j = 0; j < NT; ++j) {
                const int colt = wn * 64 + j * 16 + r16;
#pragma unroll
                for (int rr = 0; rr < 4; ++rr) {
                    float v = acc0[i][j][rr];
                    if constexpr (EPI == 1) v *= p.gam[(n0 + colt) >> 1];
                    if constexpr (EPI == 3) v = rsv * v * sigmoidf_(acc1[i][j][rr]);
                    eps[(wm * 16 + q * 4 + rr) * 132 + colt] = v;
                }
            }
            __syncthreads();
            const int row_r = tid >> 3, colg = (tid & 7) * 16;
            const int grow = m0 + (row_r >> 4) * 64 + i * 16 + (row_r & 15);
            const int gcol = n0 + colg;
            float4 f[4];
#pragma unroll
            for (int c = 0; c < 4; ++c) f[c] = *(float4*)&eps[row_r * 132 + colg + c * 4];
            const size_t ob = (size_t)grow * N + gcol;

            if constexpr (EPI == 2) {
                uint_t xp[8];
                *(uint4*)(xp)     = *(const uint4*)(p.xbf_in + ob);
                *(uint4*)(xp + 4) = *(const uint4*)(p.xbf_in + ob + 8);
#pragma unroll
                for (int c = 0; c < 4; ++c) {
                    float4 dv = *(const float4*)(p.Dv + gcol + c * 4);
                    f[c].x += dv.x * bf2f(xp[2 * c]);
                    f[c].y += dv.y * bf2f(xp[2 * c] >> 16);
                    f[c].z += dv.z * bf2f(xp[2 * c + 1]);
                    f[c].w += dv.w * bf2f(xp[2 * c + 1] >> 16);
                }
            } else if constexpr (EPI == 3) {
                uint_t xp[8];
                *(uint4*)(xp)     = *(const uint4*)(p.xbf_in + ob);
                *(uint4*)(xp + 4) = *(const uint4*)(p.xbf_in + ob + 8);
#pragma unroll
                for (int c = 0; c < 4; ++c) {
                    f[c].x += bf2f(xp[2 * c]);
                    f[c].y += bf2f(xp[2 * c] >> 16);
                    f[c].z += bf2f(xp[2 * c + 1]);
                    f[c].w += bf2f(xp[2 * c + 1] >> 16);
                }
            }
            uint4 p0, p1;
            p0.x = pack2(f[0].x, f[0].y); p0.y = pack2(f[0].z, f[0].w);
            p0.z = pack2(f[1].x, f[1].y); p0.w = pack2(f[1].z, f[1].w);
            p1.x = pack2(f[2].x, f[2].y); p1.y = pack2(f[2].z, f[2].w);
            p1.z = pack2(f[3].x, f[3].y); p1.w = pack2(f[3].z, f[3].w);
            *(uint4*)(p.obf + ob) = p0;
            *(uint4*)(p.obf + ob + 8) = p1;
        }
    }
}

// ---------------------------------------------------------------------------
// Single prep kernel: all weight bf16 packing + u cast + lambda/gamma tables.
// ---------------------------------------------------------------------------
__global__ void prep_all(const float* __restrict__ u, const float* __restrict__ enc,
                         const float* __restrict__ dec, const float* __restrict__ nu,
                         const float* __restrict__ th,
                         const float* __restrict__ Bre, const float* __restrict__ Bim,
                         const float* __restrict__ Cre, const float* __restrict__ Cim,
                         const float* __restrict__ W1, const float* __restrict__ W2,
                         ushort_t* __restrict__ WBb, ushort_t* __restrict__ Wzb,
                         ushort_t* __restrict__ W1b, ushort_t* __restrict__ W2b,
                         ushort_t* __restrict__ encb, ushort_t* __restrict__ decb,
                         ushort_t* __restrict__ ubf,
                         float* __restrict__ lre, float* __restrict__ lim,
                         float* __restrict__ gm) {
    const int idx = blockIdx.x * 256 + threadIdx.x;   // 0..1M-1
    const int k = idx & 511, n = (idx >> 9) & 511, l = idx >> 18;
    {
        const int s = n >> 1, part = n & 1;
        const float* src = part ? Bim : Bre;
        WBb[idx] = f2bf(src[((size_t)l * DS + s) * DM + k]);
    }
    {
        const int s = k >> 1, part = k & 1;
        float v = part ? -Cim[((size_t)l * DM + n) * DS + s]
                       :  Cre[((size_t)l * DM + n) * DS + s];
        Wzb[idx] = f2bf(v);
    }
    W1b[idx] = f2bf(W1[idx]);
    W2b[idx] = f2bf(W2[idx]);
    ubf[idx] = f2bf(u[idx]);
    if (idx < DM * 64) { encb[idx] = f2bf(enc[idx]); decb[idx] = f2bf(dec[idx]); }
    if (idx < NL * DS) {
        float a = expf(-expf(nu[idx])), t = expf(th[idx]);
        lre[idx] = a * cosf(t);
        lim[idx] = a * sinf(t);
        gm[idx] = sqrtf(fmaxf(0.f, 1.f - a * a));
    }
}

// ---------------------------------------------------------------------------
// Chunked 3-pass scan on interleaved bf16 (re,im) uints. 512 blocks/pass.
// ---------------------------------------------------------------------------
__global__ void scan_ends(const uint_t* __restrict__ Bu, const float* __restrict__ lre_,
                          const float* __restrict__ lim_, float* __restrict__ carry) {
    const int s = threadIdx.x;
    const int blk = blockIdx.x, b = blk >> 6, c = blk & 63;
    const float lre = lre_[s], lim = lim_[s];
    float hre = 0.f, him = 0.f;
    size_t base = ((size_t)b * SEQ + (size_t)c * LCH) * DS + s;
#pragma unroll 8
    for (int i = 0; i < LCH; ++i, base += DS) {
        uint_t u = Bu[base];
        float br = bf2f(u), bi = bf2f(u >> 16);
        float nr = fmaf(lre, hre, fmaf(-lim, him, br));
        float ni = fmaf(lre, him, fmaf(lim, hre, bi));
        hre = nr; him = ni;
    }
    carry[(size_t)blk * 512 + s] = hre;
    carry[(size_t)blk * 512 + DS + s] = him;
}

__global__ void scan_carry(float* __restrict__ carry, const float* __restrict__ lre_,
                           const float* __restrict__ lim_) {
    const int s = threadIdx.x, b = blockIdx.x;
    float pre = lre_[s], pim = lim_[s];
    for (int t = 0; t < 5; ++t) {            // lam^32 (LCH = 32 = 2^5)
        float nr = pre * pre - pim * pim, ni = 2.f * pre * pim;
        pre = nr; pim = ni;
    }
    size_t base = (size_t)b * NCH * 512 + s;
    float gre = carry[base], gim = carry[base + DS];
    for (int c = 1; c < NCH; ++c) {
        size_t id = base + (size_t)c * 512;
        float cr = carry[id], ci = carry[id + DS];
        float nr = fmaf(pre, gre, fmaf(-pim, gim, cr));
        float ni = fmaf(pre, gim, fmaf(pim, gre, ci));
        gre = nr; gim = ni;
        carry[id] = gre; carry[id + DS] = gim;
    }
}

__global__ void scan_apply(const uint_t* __restrict__ Bu, const float* __restrict__ lre_,
                           const float* __restrict__ lim_, const float* __restrict__ carry,
                           uint_t* __restrict__ h) {
    const int s = threadIdx.x;
    const int blk = blockIdx.x, b = blk >> 6, c = blk & 63;
    const float lre = lre_[s], lim = lim_[s];
    float hre = 0.f, him = 0.f;
    if (c > 0) {
        size_t cb = (size_t)(blk - 1) * 512 + s;
        hre = carry[cb]; him = carry[cb + DS];
    }
    size_t base = ((size_t)b * SEQ + (size_t)c * LCH) * DS + s;
#pragma unroll 8
    for (int i = 0; i < LCH; ++i, base += DS) {
        uint_t u = Bu[base];
        float br = bf2f(u), bi = bf2f(u >> 16);
        float nr = fmaf(lre, hre, fmaf(-lim, him, br));
        float ni = fmaf(lre, him, fmaf(lim, hre, bi));
        hre = nr; him = ni;
        h[base] = pack2(hre, him);
    }
}

// ---------------------------------------------------------------------------
extern "C" void kernel_launch(void* const* d_in, const int* in_sizes, int n_in,
                              void* d_out, int out_size, void* d_ws, size_t ws_size,
                              hipStream_t stream) {
    const float* u   = (const float*)d_in[0];
    const float* enc = (const float*)d_in[1];
    const float* dec = (const float*)d_in[2];
    const float* nu  = (const float*)d_in[3];
    const float* th  = (const float*)d_in[4];
    const float* Bre = (const float*)d_in[5];
    const float* Bim = (const float*)d_in[6];
    const float* Cre = (const float*)d_in[7];
    const float* Cim = (const float*)d_in[8];
    const float* Dp  = (const float*)d_in[9];
    const float* W1  = (const float*)d_in[10];
    const float* W2  = (const float*)d_in[11];
    const float* res = (const float*)d_in[12];
    float* out = (float*)d_out;

    const size_t MD = (size_t)MROWS * DM;
    float* carry = (float*)d_ws;                         // [8*64,512] fp32
    float* lre  = carry + (size_t)BATCH * NCH * 512;
    float* lim  = lre + NL * DS;
    float* gmt  = lim + NL * DS;
    ushort_t* xbf  = (ushort_t*)(gmt + NL * DS);         // bf16 [16384,512] each:
    ushort_t* Bubf = xbf + MD;
    ushort_t* hbf  = Bubf + MD;
    ushort_t* zbf  = hbf + MD;
    ushort_t* ubf  = zbf;                                // alias: z written after u consumed
    ushort_t* WBb  = zbf + MD;                           // weights, 4x512x512 bf16 each:
    ushort_t* Wzb  = WBb + (size_t)NL * DM * DM;
    ushort_t* W1b  = Wzb + (size_t)NL * DM * DM;
    ushort_t* W2b  = W1b + (size_t)NL * DM * DM;
    ushort_t* encb = W2b + (size_t)NL * DM * DM;         // 512x64
    ushort_t* decb = encb + DM * 64;                     // 64x512

    prep_all<<<NL * DM * DM / 256, 256, 0, stream>>>(
        u, enc, dec, nu, th, Bre, Bim, Cre, Cim, W1, W2,
        WBb, Wzb, W1b, W2b, encb, decb, ubf, lre, lim, gmt);

    const dim3 gFull(MROWS / 128, DM / 128);

    // encoder: xbf = bf16(u @ enc^T)
    {
        GemmArgs a = {};
        a.A = ubf; a.Wa = encb; a.K = 64; a.N = DM;
        a.obf = xbf;
        mgemm<128, 0, 0><<<gFull, 256, 0, stream>>>(a);
    }

    for (int k = 0; k < NL; ++k) {
        {   // Bu (interleaved re/im cols, gamma-scaled) -> Bubf
            GemmArgs a = {};
            a.A = xbf; a.Wa = WBb + (size_t)k * DM * DM; a.K = DM; a.N = DM;
            a.obf = Bubf; a.gam = gmt + k * DS;
            mgemm<128, 1, 0><<<gFull, 256, 0, stream>>>(a);
        }
        scan_ends<<<BATCH * NCH, 256, 0, stream>>>((const uint_t*)Bubf,
                                                   lre + k * DS, lim + k * DS, carry);
        scan_carry<<<BATCH, 256, 0, stream>>>(carry, lre + k * DS, lim + k * DS);
        scan_apply<<<BATCH * NCH, 256, 0, stream>>>((const uint_t*)Bubf,
                                                    lre + k * DS, lim + k * DS, carry,
                                                    (uint_t*)hbf);
        {   // z = Re(h @ C^T) + D*x  -> zbf
            GemmArgs a = {};
            a.A = hbf; a.Wa = Wzb + (size_t)k * DM * DM; a.K = DM; a.N = DM;
            a.obf = zbf; a.xbf_in = xbf; a.Dv = Dp + k * DM;
            mgemm<128, 2, 0><<<gFull, 256, 0, stream>>>(a);
        }
        {   // xbf += sig(res)*[(z@W1^T)*sigmoid(z@W2^T)]   (bf16 RMW)
            GemmArgs a = {};
            a.A = zbf; a.Wa = W1b + (size_t)k * DM * DM; a.Wb = W2b + (size_t)k * DM * DM;
            a.K = DM; a.N = DM;
            a.obf = xbf; a.xbf_in = xbf; a.resp = res; a.layer = k;
            mgemm<128, 3, 1><<<gFull, 256, 0, stream>>>(a);
        }
    }
    {   // decoder: out = x @ dec^T
        GemmArgs a = {};
        a.A = xbf; a.Wa = decb; a.K = DM; a.N = 64;
        a.of32 = out;
        mgemm<64, 4, 0><<<dim3(MROWS / 128, 1), 256, 0, stream>>>(a);
    }
}